// Round 7
// baseline (147.886 us; speedup 1.0000x reference)
//
#include <hip/hip_runtime.h>
#include <hip/hip_fp16.h>

#define ODIM 128
#define INV_KEEP 1.1111112f   // float(1.0/0.9)

#ifndef __has_builtin
#define __has_builtin(x) 0
#endif
#if __has_builtin(__builtin_amdgcn_make_buffer_rsrc) && __has_builtin(__builtin_amdgcn_raw_buffer_load_b32)
#define USE_BUFFER_RSRC 1
#else
#define USE_BUFFER_RSRC 0
#endif

// ---------- Fused prep kernel ----------
// Blocks [0, cvt_blocks): convert f32 W -> f16 into workspace (4 elems/thread).
// Blocks [cvt_blocks, ...): per-nnz (4/thread):
//   packed[i] = (col[i] << 16) | f16bits(mask ? val/keep : 0)
//   row_ptr scatter from sorted rows[]: row_ptr[r] = first i with rows[i] >= r.
__global__ void prep_kernel(const float* __restrict__ w, __half* __restrict__ wh,
                            int w_elems,
                            const int*   __restrict__ rows,
                            const int*   __restrict__ cols,
                            const float* __restrict__ vals,
                            const int*   __restrict__ mask,
                            int*         __restrict__ row_ptr,
                            unsigned*    __restrict__ packed,
                            int nnz, int n_nodes, int cvt_blocks) {
    if ((int)blockIdx.x < cvt_blocks) {
        int i4 = (blockIdx.x * 256 + threadIdx.x) * 4;
        if (i4 + 3 < w_elems) {
            float4 f = *(const float4*)(w + i4);
            *(__half2*)(wh + i4)     = __floats2half2_rn(f.x, f.y);
            *(__half2*)(wh + i4 + 2) = __floats2half2_rn(f.z, f.w);
        } else {
            for (int k = i4; k < w_elems; ++k) wh[k] = __float2half(w[k]);
        }
    } else {
        int i4 = ((blockIdx.x - cvt_blocks) * 256 + threadIdx.x) * 4;
        if (i4 >= nnz) return;
        int rprev = (i4 == 0) ? -1 : rows[i4 - 1];
        #pragma unroll
        for (int k = 0; k < 4; ++k) {
            int i = i4 + k;
            if (i < nnz) {
                float vmv   = mask[i] ? vals[i] * INV_KEEP : 0.0f;
                unsigned hv = (unsigned)__half_as_ushort(__float2half(vmv));
                packed[i]   = ((unsigned)cols[i] << 16) | hv;
                int rc = rows[i];
                for (int r = rprev + 1; r <= rc; ++r) row_ptr[r] = i;
                if (i == nnz - 1)
                    for (int r = rc + 1; r <= n_nodes; ++r) row_ptr[r] = nnz;
                rprev = rc;
            }
        }
    }
}

// ---------- Main SpMM (fast path): one wave per output row ----------
// Lane i cooperatively loads packed nnz i of the row (1 coalesced load);
// per-nnz (col,v) extracted with ONE v_readlane. W gather uses a buffer
// descriptor: SGPR soffset = col*256B, loop-invariant VGPR voff = lane*4B
// -> zero per-nnz vector address math. Main batches of 8 are predicate-free;
// one padded tail batch (pads gather row 0 with v=+0, harmless).
__global__ void __launch_bounds__(256, 8)
spmm_f16_kernel(const unsigned* __restrict__ packed,
                const __half*   __restrict__ wh,
                const float*    __restrict__ bias,
                const int*      __restrict__ row_ptr,
                float*          __restrict__ out, int n_nodes) {
    const int wave = threadIdx.x >> 6;
    const int lane = threadIdx.x & 63;
    const int row  = blockIdx.x * 4 + wave;
    if (row >= n_nodes) return;

    const int i0 = __builtin_amdgcn_readfirstlane(row_ptr[row]);
    const int i1 = __builtin_amdgcn_readfirstlane(row_ptr[row + 1]);

    float2 acc = ((const float2*)bias)[lane];

#if USE_BUFFER_RSRC
    __amdgpu_buffer_rsrc_t srd =
        __builtin_amdgcn_make_buffer_rsrc((void*)wh, (short)0, -1, 0x00020000);
#endif
    const int voff = lane * 4;     // byte offset of this lane's half2 within a W row

    for (int base = i0; base < i1; base += 64) {
        const int rem = i1 - base;
        const int cnt = rem < 64 ? rem : 64;              // SGPR
        const int idx = base + lane;
        const unsigned pk_lane = packed[idx < i1 ? idx : (i1 - 1)];

        const int nb = cnt & ~7;                          // full batches
        int k0 = 0;
        for (; k0 < nb; k0 += 8) {
            unsigned h[8];
            unsigned short vh[8];
            #pragma unroll
            for (int k = 0; k < 8; ++k) {
                const unsigned pk = (unsigned)__builtin_amdgcn_readlane(pk_lane, k0 + k);
                vh[k] = (unsigned short)(pk & 0xffffu);
                const int soff = (int)((pk >> 16) << 8);  // col * 256B (SGPR)
#if USE_BUFFER_RSRC
                h[k] = __builtin_amdgcn_raw_buffer_load_b32(srd, voff, soff, 0);
#else
                h[k] = *(const unsigned*)((const char*)wh + (size_t)(unsigned)soff + voff);
#endif
            }
            #pragma unroll
            for (int k = 0; k < 8; ++k) {
                const __half2 w2 = *(const __half2*)&h[k];
                const float   v  = __half2float(__ushort_as_half(vh[k]));
                acc.x = fmaf(v, __half2float(__low2half(w2)),  acc.x);
                acc.y = fmaf(v, __half2float(__high2half(w2)), acc.y);
            }
        }
        if (k0 < cnt) {   // padded tail: 1..7 real nnz
            unsigned h[8];
            unsigned short vh[8];
            #pragma unroll
            for (int k = 0; k < 8; ++k) {
                const int kk = k0 + k;                    // <= 63 guaranteed
                unsigned pk = (unsigned)__builtin_amdgcn_readlane(pk_lane, kk);
                pk = (kk < cnt) ? pk : 0u;                // pad: col 0, v=+0
                vh[k] = (unsigned short)(pk & 0xffffu);
                const int soff = (int)((pk >> 16) << 8);
#if USE_BUFFER_RSRC
                h[k] = __builtin_amdgcn_raw_buffer_load_b32(srd, voff, soff, 0);
#else
                h[k] = *(const unsigned*)((const char*)wh + (size_t)(unsigned)soff + voff);
#endif
            }
            #pragma unroll
            for (int k = 0; k < 8; ++k) {
                const __half2 w2 = *(const __half2*)&h[k];
                const float   v  = __half2float(__ushort_as_half(vh[k]));
                acc.x = fmaf(v, __half2float(__low2half(w2)),  acc.x);
                acc.y = fmaf(v, __half2float(__high2half(w2)), acc.y);
            }
        }
    }

    union { float2 f2; unsigned long long u; } pkst;
    pkst.f2 = acc;
    __builtin_nontemporal_store(pkst.u,
        (unsigned long long*)(out + (size_t)row * ODIM + 2 * lane));
}

// ---------- Fallback (no workspace): f32 W, binary search ----------
__global__ void __launch_bounds__(256, 8)
spmm_f32_kernel(const float* __restrict__ vals,
                const int*   __restrict__ rows,
                const int*   __restrict__ cols,
                const int*   __restrict__ mask,
                const float* __restrict__ wmat,
                const float* __restrict__ bias,
                float*       __restrict__ out,
                int nnz, int n_nodes) {
    const int wave = threadIdx.x >> 6;
    const int lane = threadIdx.x & 63;
    const int row  = blockIdx.x * 4 + wave;
    if (row >= n_nodes) return;
    auto lb = [&](int target) {
        int lo = 0, hi = nnz;
        while (lo < hi) {
            int mid = (lo + hi) >> 1;
            if (rows[mid] < target) lo = mid + 1; else hi = mid;
        }
        return lo;
    };
    const int i0 = __builtin_amdgcn_readfirstlane(lb(row));
    const int i1 = __builtin_amdgcn_readfirstlane(lb(row + 1));
    float2 acc = ((const float2*)bias)[lane];
    for (int i = i0; i < i1; ++i) {
        int c = cols[i];
        float v = mask[i] ? vals[i] * INV_KEEP : 0.0f;
        float2 w = *(const float2*)(wmat + (size_t)c * ODIM + 2 * lane);
        acc.x = fmaf(v, w.x, acc.x);
        acc.y = fmaf(v, w.y, acc.y);
    }
    *(float2*)(out + (size_t)row * ODIM + 2 * lane) = acc;
}

extern "C" void kernel_launch(void* const* d_in, const int* in_sizes, int n_in,
                              void* d_out, int out_size, void* d_ws, size_t ws_size,
                              hipStream_t stream) {
    const float* vals = (const float*)d_in[0];
    const int*   rows = (const int*)  d_in[1];
    const int*   cols = (const int*)  d_in[2];
    const int*   mask = (const int*)  d_in[3];
    const float* W    = (const float*)d_in[4];
    const float* bias = (const float*)d_in[5];
    float*       out  = (float*)d_out;

    const int nnz       = in_sizes[0];
    const int w_elems   = in_sizes[4];           // INPUT_DIM * OUTPUT_DIM
    const int n_nodes   = out_size / ODIM;
    const int input_dim = w_elems / ODIM;

    // workspace layout: [W f16 | row_ptr | packed], each 256B aligned
    const size_t wh_bytes = ((size_t)w_elems * sizeof(__half) + 255) & ~(size_t)255;
    const size_t rp_bytes = ((size_t)(n_nodes + 1) * sizeof(int) + 255) & ~(size_t)255;
    const size_t pk_bytes = (size_t)nnz * sizeof(unsigned);

    const bool fast = (input_dim <= 65536) &&
                      (ws_size >= wh_bytes + rp_bytes + pk_bytes);
    if (fast) {
        __half*   wh      = (__half*)d_ws;
        int*      row_ptr = (int*)((char*)d_ws + wh_bytes);
        unsigned* packed  = (unsigned*)((char*)d_ws + wh_bytes + rp_bytes);

        const int cvt_blocks = (w_elems / 4 + 255) / 256;
        const int nz_blocks  = ((nnz + 3) / 4 + 255) / 256;
        prep_kernel<<<cvt_blocks + nz_blocks, 256, 0, stream>>>(
            W, wh, w_elems, rows, cols, vals, mask, row_ptr, packed,
            nnz, n_nodes, cvt_blocks);

        const int blocks = (n_nodes + 3) / 4;   // 4 rows (waves) per block
        spmm_f16_kernel<<<blocks, 256, 0, stream>>>(
            packed, wh, bias, row_ptr, out, n_nodes);
    } else {
        const int blocks = (n_nodes + 3) / 4;
        spmm_f32_kernel<<<blocks, 256, 0, stream>>>(
            vals, rows, cols, mask, W, bias, out, nnz, n_nodes);
    }
}